// Round 1
// baseline (1018.536 us; speedup 1.0000x reference)
//
#include <hip/hip_runtime.h>
#include <math.h>

// Problem constants: B=4, H=8, L=512, HD=64, D=512, RHO=0.1
// Workspace layout (floats):
//   Q   : 1M   [BH][512][64]
//   K   : 1M
//   V   : 1M
//   S   : 8M   [BH][512][512]   (later reused for J = S_jump, then softmax'd in place)
//   A   : 8M   (adjacency, then A_hat in place)
//   T   : 8M   (A_hat @ S)
//   R   : 16K  (row inv-sqrt degrees)
//   O   : 1M   [BH][512][64]
// total ~117.6 MB

// ---------------------------------------------------------------------------
// Generic 128x128-tile fp32 GEMM, BK=16, 256 threads, 8x8 micro-tile.
// BT=1: C = A * B^T (B is N x K row-major). BT=0: C = A * B (K x N).
// REMAP=1: output scatter for projections: m=(b,l), n=(h,d) -> [(b*8+h)*512+l]*64+d
// ---------------------------------------------------------------------------
template<int BT, int REMAP>
__global__ __launch_bounds__(256)
void gemm128(const float* __restrict__ Ap, const float* __restrict__ Bp,
             float* __restrict__ Cp, int M, int N, int K,
             long sA, long sB, long sC, float scale)
{
    const float* A  = Ap + (long)blockIdx.z * sA;
    const float* Bm = Bp + (long)blockIdx.z * sB;
    float*       C  = Cp + (long)blockIdx.z * sC;

    __shared__ float As[16][132];
    __shared__ float Bs[16][132];

    const int tid = threadIdx.x;
    const int tx = tid & 15, ty = tid >> 4;
    const int m0 = blockIdx.y << 7, n0 = blockIdx.x << 7;

    float acc[8][8] = {};

    for (int k0 = 0; k0 < K; k0 += 16) {
        const int r = tid >> 1, c = (tid & 1) << 3;
        float4 a0 = *(const float4*)(A + (long)(m0 + r) * K + k0 + c);
        float4 a1 = *(const float4*)(A + (long)(m0 + r) * K + k0 + c + 4);
        float4 b0, b1;
        int rb = 0, cb = 0;
        if (BT) {
            b0 = *(const float4*)(Bm + (long)(n0 + r) * K + k0 + c);
            b1 = *(const float4*)(Bm + (long)(n0 + r) * K + k0 + c + 4);
        } else {
            rb = tid >> 4; cb = (tid & 15) << 3;
            b0 = *(const float4*)(Bm + (long)(k0 + rb) * N + n0 + cb);
            b1 = *(const float4*)(Bm + (long)(k0 + rb) * N + n0 + cb + 4);
        }

        As[c + 0][r] = a0.x; As[c + 1][r] = a0.y; As[c + 2][r] = a0.z; As[c + 3][r] = a0.w;
        As[c + 4][r] = a1.x; As[c + 5][r] = a1.y; As[c + 6][r] = a1.z; As[c + 7][r] = a1.w;
        if (BT) {
            Bs[c + 0][r] = b0.x; Bs[c + 1][r] = b0.y; Bs[c + 2][r] = b0.z; Bs[c + 3][r] = b0.w;
            Bs[c + 4][r] = b1.x; Bs[c + 5][r] = b1.y; Bs[c + 6][r] = b1.z; Bs[c + 7][r] = b1.w;
        } else {
            *(float4*)&Bs[rb][cb]     = b0;
            *(float4*)&Bs[rb][cb + 4] = b1;
        }
        __syncthreads();

        #pragma unroll
        for (int kk = 0; kk < 16; ++kk) {
            float a[8], b[8];
            *(float4*)&a[0] = *(const float4*)&As[kk][ty << 3];
            *(float4*)&a[4] = *(const float4*)&As[kk][(ty << 3) + 4];
            *(float4*)&b[0] = *(const float4*)&Bs[kk][tx << 3];
            *(float4*)&b[4] = *(const float4*)&Bs[kk][(tx << 3) + 4];
            #pragma unroll
            for (int i = 0; i < 8; ++i)
                #pragma unroll
                for (int j = 0; j < 8; ++j)
                    acc[i][j] = fmaf(a[i], b[j], acc[i][j]);
        }
        __syncthreads();
    }

    #pragma unroll
    for (int i = 0; i < 8; ++i) {
        const int m = m0 + (ty << 3) + i;
        #pragma unroll
        for (int j4 = 0; j4 < 8; j4 += 4) {
            float4 v = make_float4(acc[i][j4 + 0] * scale, acc[i][j4 + 1] * scale,
                                   acc[i][j4 + 2] * scale, acc[i][j4 + 3] * scale);
            if (REMAP) {
                const int b = m >> 9, l = m & 511;
                const int n = n0 + (tx << 3) + j4;
                const int h = n >> 6, d = n & 63;
                *(float4*)(C + ((long)((b * 8 + h) * 512 + l)) * 64 + d) = v;
            } else {
                *(float4*)(C + (long)m * N + n0 + (tx << 3) + j4) = v;
            }
        }
    }
}

// ---------------------------------------------------------------------------
// Adjacency: A[i,k] = (1/512) * sum_j u, u = (S_ij/8)*(S_kj/8) if u > 0.1, i!=k
// 64x64 tile per block, 4x4 micro-tile. Prescale by 1/8 in LDS (exact pow2,
// preserves reference rounding of S_ij*S_kj/64).
// ---------------------------------------------------------------------------
__global__ __launch_bounds__(256)
void adj_kernel(const float* __restrict__ S, float* __restrict__ A)
{
    const int bh = blockIdx.z;
    const float* __restrict__ Sh = S + (long)bh * 262144;
    float* __restrict__ Ah = A + (long)bh * 262144;

    __shared__ float Ls[16][68];
    __shared__ float Rs[16][68];

    const int tid = threadIdx.x;
    const int tx = tid & 15, ty = tid >> 4;
    const int i0 = blockIdx.y << 6, k0 = blockIdx.x << 6;

    float acc[4][4] = {};

    for (int j0 = 0; j0 < 512; j0 += 16) {
        const int r = tid >> 2, c4 = (tid & 3) << 2;
        float4 av = *(const float4*)(Sh + (long)(i0 + r) * 512 + j0 + c4);
        float4 bv = *(const float4*)(Sh + (long)(k0 + r) * 512 + j0 + c4);

        Ls[c4 + 0][r] = av.x * 0.125f; Ls[c4 + 1][r] = av.y * 0.125f;
        Ls[c4 + 2][r] = av.z * 0.125f; Ls[c4 + 3][r] = av.w * 0.125f;
        Rs[c4 + 0][r] = bv.x * 0.125f; Rs[c4 + 1][r] = bv.y * 0.125f;
        Rs[c4 + 2][r] = bv.z * 0.125f; Rs[c4 + 3][r] = bv.w * 0.125f;
        __syncthreads();

        #pragma unroll
        for (int jj = 0; jj < 16; ++jj) {
            float a[4], b[4];
            *(float4*)a = *(const float4*)&Ls[jj][ty << 2];
            *(float4*)b = *(const float4*)&Rs[jj][tx << 2];
            #pragma unroll
            for (int i = 0; i < 4; ++i)
                #pragma unroll
                for (int j = 0; j < 4; ++j) {
                    float u = a[i] * b[j];
                    acc[i][j] += (u > 0.1f) ? u : 0.0f;
                }
        }
        __syncthreads();
    }

    const float inv = 1.0f / 512.0f;
    #pragma unroll
    for (int i = 0; i < 4; ++i) {
        const int gi = i0 + (ty << 2) + i;
        float4 v;
        float* pv = &v.x;
        #pragma unroll
        for (int j = 0; j < 4; ++j) {
            const int gk = k0 + (tx << 2) + j;
            pv[j] = (gi == gk) ? 0.0f : acc[i][j] * inv;
        }
        *(float4*)(Ah + (long)gi * 512 + k0 + (tx << 2)) = v;
    }
}

// ---------------------------------------------------------------------------
// Row degree: R[row] = 1/sqrt(clip(1 + sum_k A[row,k], 1e-6)) ; one wave/row
// ---------------------------------------------------------------------------
__global__ __launch_bounds__(256)
void rowsum_kernel(const float* __restrict__ A, float* __restrict__ R)
{
    const int row = (blockIdx.x << 2) + (threadIdx.x >> 6);
    const int lane = threadIdx.x & 63;
    const float* p = A + (long)row * 512;
    float s = 0.0f;
    #pragma unroll
    for (int t = 0; t < 8; ++t) s += p[lane + (t << 6)];
    #pragma unroll
    for (int off = 32; off; off >>= 1) s += __shfl_xor(s, off, 64);
    if (lane == 0) R[row] = 1.0f / sqrtf(fmaxf(1.0f + s, 1e-6f));
}

// ---------------------------------------------------------------------------
// A_hat[i,k] = R[i]*R[k]*(A[i,k] + (i==k)) in place
// ---------------------------------------------------------------------------
__global__ __launch_bounds__(256)
void ahat_kernel(float* __restrict__ A, const float* __restrict__ R)
{
    const long i4 = ((long)blockIdx.x * 256 + threadIdx.x) << 2;
    const long off = i4 & 262143;
    const long bh = i4 >> 18;
    const int i = (int)(off >> 9);
    const int k = (int)(off & 511);
    const float ri = R[(bh << 9) + i];
    const float* Rk = R + (bh << 9) + k;
    float4 v = *(float4*)(A + i4);
    v.x = ri * Rk[0] * (v.x + ((k + 0) == i ? 1.0f : 0.0f));
    v.y = ri * Rk[1] * (v.y + ((k + 1) == i ? 1.0f : 0.0f));
    v.z = ri * Rk[2] * (v.z + ((k + 2) == i ? 1.0f : 0.0f));
    v.w = ri * Rk[3] * (v.w + ((k + 3) == i ? 1.0f : 0.0f));
    *(float4*)(A + i4) = v;
}

// ---------------------------------------------------------------------------
// Row softmax over 512, in place. One block (256 threads) per row.
// ---------------------------------------------------------------------------
__global__ __launch_bounds__(256)
void softmax_kernel(float* __restrict__ P)
{
    float* p = P + (long)blockIdx.x * 512;
    const int t = threadIdx.x;
    float v0 = p[t], v1 = p[t + 256];
    __shared__ float red[256];
    red[t] = fmaxf(v0, v1);
    __syncthreads();
    #pragma unroll
    for (int s = 128; s > 0; s >>= 1) {
        if (t < s) red[t] = fmaxf(red[t], red[t + s]);
        __syncthreads();
    }
    const float mx = red[0];
    __syncthreads();
    const float e0 = __expf(v0 - mx), e1 = __expf(v1 - mx);
    red[t] = e0 + e1;
    __syncthreads();
    #pragma unroll
    for (int s = 128; s > 0; s >>= 1) {
        if (t < s) red[t] += red[t + s];
        __syncthreads();
    }
    const float inv = 1.0f / red[0];
    p[t] = e0 * inv;
    p[t + 256] = e1 * inv;
}

// ---------------------------------------------------------------------------
// O = P @ V per head: M=512, N=64, K=512. 64x64 tile, 4x4 micro.
// ---------------------------------------------------------------------------
__global__ __launch_bounds__(256)
void gemm_pv(const float* __restrict__ P, const float* __restrict__ V,
             float* __restrict__ O)
{
    const int bh = blockIdx.z;
    const float* Pp = P + (long)bh * 262144;
    const float* Vp = V + (long)bh * 32768;
    float* Op = O + (long)bh * 32768;

    __shared__ float Ps[16][68];
    __shared__ float Vs[16][68];

    const int tid = threadIdx.x;
    const int tx = tid & 15, ty = tid >> 4;
    const int m0 = blockIdx.y << 6;

    float acc[4][4] = {};

    for (int k0 = 0; k0 < 512; k0 += 16) {
        const int r = tid >> 2, c4 = (tid & 3) << 2;
        float4 av = *(const float4*)(Pp + (long)(m0 + r) * 512 + k0 + c4);
        const int rb = tid >> 4, cb = (tid & 15) << 2;
        float4 bv = *(const float4*)(Vp + (long)(k0 + rb) * 64 + cb);

        Ps[c4 + 0][r] = av.x; Ps[c4 + 1][r] = av.y;
        Ps[c4 + 2][r] = av.z; Ps[c4 + 3][r] = av.w;
        *(float4*)&Vs[rb][cb] = bv;
        __syncthreads();

        #pragma unroll
        for (int kk = 0; kk < 16; ++kk) {
            float a[4], b[4];
            *(float4*)a = *(const float4*)&Ps[kk][ty << 2];
            *(float4*)b = *(const float4*)&Vs[kk][tx << 2];
            #pragma unroll
            for (int i = 0; i < 4; ++i)
                #pragma unroll
                for (int j = 0; j < 4; ++j)
                    acc[i][j] = fmaf(a[i], b[j], acc[i][j]);
        }
        __syncthreads();
    }

    #pragma unroll
    for (int i = 0; i < 4; ++i) {
        float4 v = make_float4(acc[i][0], acc[i][1], acc[i][2], acc[i][3]);
        *(float4*)(Op + (long)(m0 + (ty << 2) + i) * 64 + (tx << 2)) = v;
    }
}

// ---------------------------------------------------------------------------
// Transpose O [BH][L][HD] -> Of [B][L][H*HD]
// ---------------------------------------------------------------------------
__global__ __launch_bounds__(256)
void transO_kernel(const float* __restrict__ O, float* __restrict__ Of)
{
    const long i4 = ((long)blockIdx.x * 256 + threadIdx.x) << 2;
    const int d = (int)(i4 & 63);
    const long rest = i4 >> 6;          // (b*8+h)*512 + l
    const int l = (int)(rest & 511);
    const long bh = rest >> 9;
    const int h = (int)(bh & 7);
    const long b = bh >> 3;
    const float4 v = *(const float4*)(O + i4);
    *(float4*)(Of + (((b << 9) + l) << 9) + (h << 6) + d) = v;
}

// ---------------------------------------------------------------------------
extern "C" void kernel_launch(void* const* d_in, const int* in_sizes, int n_in,
                              void* d_out, int out_size, void* d_ws, size_t ws_size,
                              hipStream_t stream)
{
    const float* x  = (const float*)d_in[0];
    const float* Wq = (const float*)d_in[1];
    const float* Wk = (const float*)d_in[2];
    const float* Wv = (const float*)d_in[3];
    const float* Wo = (const float*)d_in[4];
    float* out = (float*)d_out;

    float* ws = (float*)d_ws;
    float* Q  = ws;                       // 1M floats
    float* Kt = Q  + (1u << 20);          // 1M
    float* V  = Kt + (1u << 20);          // 1M
    float* S  = V  + (1u << 20);          // 8M
    float* Am = S  + (8u << 20);          // 8M
    float* T  = Am + (8u << 20);          // 8M
    float* R  = T  + (8u << 20);          // 16K
    float* O  = R  + 16384;               // 1M

    dim3 blk(256);

    // 1) Q/K/V projections: [B*L,512] x [512,512] -> [BH][L][HD]
    gemm128<0, 1><<<dim3(4, 16, 1), blk, 0, stream>>>(x, Wq, Q,  2048, 512, 512, 0, 0, 0, 1.0f);
    gemm128<0, 1><<<dim3(4, 16, 1), blk, 0, stream>>>(x, Wk, Kt, 2048, 512, 512, 0, 0, 0, 1.0f);
    gemm128<0, 1><<<dim3(4, 16, 1), blk, 0, stream>>>(x, Wv, V,  2048, 512, 512, 0, 0, 0, 1.0f);

    // 2) S = Q K^T per head
    gemm128<1, 0><<<dim3(4, 4, 32), blk, 0, stream>>>(Q, Kt, S, 512, 512, 64,
                                                      32768, 32768, 262144, 1.0f);

    // 3) adjacency A (diag 0, thresholded, /L)
    adj_kernel<<<dim3(8, 8, 32), blk, 0, stream>>>(S, Am);

    // 4) row degrees -> R = D^-1/2
    rowsum_kernel<<<dim3(4096), blk, 0, stream>>>(Am, R);

    // 5) A_hat in place
    ahat_kernel<<<dim3(8192), blk, 0, stream>>>(Am, R);

    // 6) T = A_hat @ S
    gemm128<0, 0><<<dim3(4, 4, 32), blk, 0, stream>>>(Am, S, T, 512, 512, 512,
                                                      262144, 262144, 262144, 1.0f);

    // 7) J = T @ A_hat^T / 8  (into S buffer)
    gemm128<1, 0><<<dim3(4, 4, 32), blk, 0, stream>>>(T, Am, S, 512, 512, 512,
                                                      262144, 262144, 262144, 0.125f);

    // 8) softmax rows of J (in place in S)
    softmax_kernel<<<dim3(16384), blk, 0, stream>>>(S);

    // 9) O = P @ V
    gemm_pv<<<dim3(1, 8, 32), blk, 0, stream>>>(S, V, O);

    // 10) O -> Of (reuse Q buffer)
    transO_kernel<<<dim3(1024), blk, 0, stream>>>(O, Q);

    // 11) out = Of @ Wo
    gemm128<0, 0><<<dim3(4, 16, 1), blk, 0, stream>>>(Q, Wo, out, 2048, 512, 512,
                                                      0, 0, 0, 1.0f);
}

// Round 2
// 950.480 us; speedup vs baseline: 1.0716x; 1.0716x over previous
//
#include <hip/hip_runtime.h>
#include <math.h>

// Problem constants: B=4, H=8, L=512, HD=64, D=512, RHO=0.1
// Workspace layout (floats):
//   Q   : 1M   [BH][512][64]
//   K   : 1M
//   V   : 1M
//   S   : 8M   [BH][512][512]   (later reused for J = S_jump, then softmax'd in place)
//   A   : 8M   (adjacency, then A_hat in place)
//   T   : 8M   (A_hat @ S)
//   R   : 16K  (row inv-sqrt degrees)
//   O   : 1M   [BH][512][64]

// ---------------------------------------------------------------------------
// Generic 128x128-tile fp32 GEMM, BK=16, 256 threads, 8x8 micro-tile.
// BT=1: C = A * B^T (B is N x K row-major). BT=0: C = A * B (K x N).
// REMAP=1: output scatter for projections: m=(b,l), n=(h,d) -> [(b*8+h)*512+l]*64+d
// ---------------------------------------------------------------------------
template<int BT, int REMAP>
__global__ __launch_bounds__(256)
void gemm128(const float* __restrict__ Ap, const float* __restrict__ Bp,
             float* __restrict__ Cp, int M, int N, int K,
             long sA, long sB, long sC, float scale)
{
    const float* A  = Ap + (long)blockIdx.z * sA;
    const float* Bm = Bp + (long)blockIdx.z * sB;
    float*       C  = Cp + (long)blockIdx.z * sC;

    __shared__ float As[16][132];
    __shared__ float Bs[16][132];

    const int tid = threadIdx.x;
    const int tx = tid & 15, ty = tid >> 4;
    const int m0 = blockIdx.y << 7, n0 = blockIdx.x << 7;

    float acc[8][8] = {};

    for (int k0 = 0; k0 < K; k0 += 16) {
        const int r = tid >> 1, c = (tid & 1) << 3;
        float4 a0 = *(const float4*)(A + (long)(m0 + r) * K + k0 + c);
        float4 a1 = *(const float4*)(A + (long)(m0 + r) * K + k0 + c + 4);
        float4 b0, b1;
        int rb = 0, cb = 0;
        if (BT) {
            b0 = *(const float4*)(Bm + (long)(n0 + r) * K + k0 + c);
            b1 = *(const float4*)(Bm + (long)(n0 + r) * K + k0 + c + 4);
        } else {
            rb = tid >> 4; cb = (tid & 15) << 3;
            b0 = *(const float4*)(Bm + (long)(k0 + rb) * N + n0 + cb);
            b1 = *(const float4*)(Bm + (long)(k0 + rb) * N + n0 + cb + 4);
        }

        As[c + 0][r] = a0.x; As[c + 1][r] = a0.y; As[c + 2][r] = a0.z; As[c + 3][r] = a0.w;
        As[c + 4][r] = a1.x; As[c + 5][r] = a1.y; As[c + 6][r] = a1.z; As[c + 7][r] = a1.w;
        if (BT) {
            Bs[c + 0][r] = b0.x; Bs[c + 1][r] = b0.y; Bs[c + 2][r] = b0.z; Bs[c + 3][r] = b0.w;
            Bs[c + 4][r] = b1.x; Bs[c + 5][r] = b1.y; Bs[c + 6][r] = b1.z; Bs[c + 7][r] = b1.w;
        } else {
            *(float4*)&Bs[rb][cb]     = b0;
            *(float4*)&Bs[rb][cb + 4] = b1;
        }
        __syncthreads();

        #pragma unroll
        for (int kk = 0; kk < 16; ++kk) {
            float a[8], b[8];
            *(float4*)&a[0] = *(const float4*)&As[kk][ty << 3];
            *(float4*)&a[4] = *(const float4*)&As[kk][(ty << 3) + 4];
            *(float4*)&b[0] = *(const float4*)&Bs[kk][tx << 3];
            *(float4*)&b[4] = *(const float4*)&Bs[kk][(tx << 3) + 4];
            #pragma unroll
            for (int i = 0; i < 8; ++i)
                #pragma unroll
                for (int j = 0; j < 8; ++j)
                    acc[i][j] = fmaf(a[i], b[j], acc[i][j]);
        }
        __syncthreads();
    }

    #pragma unroll
    for (int i = 0; i < 8; ++i) {
        const int m = m0 + (ty << 3) + i;
        #pragma unroll
        for (int j4 = 0; j4 < 8; j4 += 4) {
            float4 v = make_float4(acc[i][j4 + 0] * scale, acc[i][j4 + 1] * scale,
                                   acc[i][j4 + 2] * scale, acc[i][j4 + 3] * scale);
            if (REMAP) {
                const int b = m >> 9, l = m & 511;
                const int n = n0 + (tx << 3) + j4;
                const int h = n >> 6, d = n & 63;
                *(float4*)(C + ((long)((b * 8 + h) * 512 + l)) * 64 + d) = v;
            } else {
                *(float4*)(C + (long)m * N + n0 + (tx << 3) + j4) = v;
            }
        }
    }
}

// ---------------------------------------------------------------------------
// Adjacency: A[i,k] = (1/512) * sum_j u, u = (S_ij/8)*(S_kj/8) if u > 0.1, i!=k
// A is exactly symmetric (same products, same j summation order) -> compute
// only upper-triangle 64x64 tile pairs (36 of 64) and mirror the write.
// Branchless sign-mask select (no vcc dependency):
//   t = 0.1 - u; m = sign(t) ? ~0 : 0; acc += u & m   (bit-exact vs u > 0.1)
// ---------------------------------------------------------------------------
__global__ __launch_bounds__(256)
void adj_kernel(const float* __restrict__ S, float* __restrict__ A)
{
    const int bh = blockIdx.z;
    const float* __restrict__ Sh = S + (long)bh * 262144;
    float* __restrict__ Ah = A + (long)bh * 262144;

    // decode upper-triangle tile pair: blockIdx.x in [0,36) -> (ti <= tk)
    int ti = 0, rem = blockIdx.x;
    while (rem >= 8 - ti) { rem -= 8 - ti; ++ti; }
    const int tk = ti + rem;

    __shared__ float Ls[16][68];
    __shared__ float Rs[16][68];

    const int tid = threadIdx.x;
    const int tx = tid & 15, ty = tid >> 4;
    const int i0 = ti << 6, k0 = tk << 6;

    float acc[4][4] = {};

    for (int j0 = 0; j0 < 512; j0 += 16) {
        const int r = tid >> 2, c4 = (tid & 3) << 2;
        float4 av = *(const float4*)(Sh + (long)(i0 + r) * 512 + j0 + c4);
        float4 bv = *(const float4*)(Sh + (long)(k0 + r) * 512 + j0 + c4);

        Ls[c4 + 0][r] = av.x * 0.125f; Ls[c4 + 1][r] = av.y * 0.125f;
        Ls[c4 + 2][r] = av.z * 0.125f; Ls[c4 + 3][r] = av.w * 0.125f;
        Rs[c4 + 0][r] = bv.x * 0.125f; Rs[c4 + 1][r] = bv.y * 0.125f;
        Rs[c4 + 2][r] = bv.z * 0.125f; Rs[c4 + 3][r] = bv.w * 0.125f;
        __syncthreads();

        #pragma unroll
        for (int jj = 0; jj < 16; ++jj) {
            float a[4], b[4];
            *(float4*)a = *(const float4*)&Ls[jj][ty << 2];
            *(float4*)b = *(const float4*)&Rs[jj][tx << 2];
            #pragma unroll
            for (int i = 0; i < 4; ++i)
                #pragma unroll
                for (int j = 0; j < 4; ++j) {
                    const float u = a[i] * b[j];
                    const float t = 0.1f - u;
                    const int  m = __float_as_int(t) >> 31;
                    acc[i][j] += __int_as_float(__float_as_int(u) & m);
                }
        }
        __syncthreads();
    }

    const float inv = 1.0f / 512.0f;
    float vals[4][4];
    #pragma unroll
    for (int i = 0; i < 4; ++i) {
        const int gi = i0 + (ty << 2) + i;
        float4 v;
        float* pv = &v.x;
        #pragma unroll
        for (int j = 0; j < 4; ++j) {
            const int gk = k0 + (tx << 2) + j;
            pv[j] = (gi == gk) ? 0.0f : acc[i][j] * inv;
            vals[i][j] = pv[j];
        }
        *(float4*)(Ah + (long)gi * 512 + k0 + (tx << 2)) = v;
    }

    if (ti != tk) {
        // mirror: A[k,i] = A[i,k] (exact)
        #pragma unroll
        for (int i = 0; i < 4; ++i) {
            const int gi = i0 + (ty << 2) + i;
            #pragma unroll
            for (int j = 0; j < 4; ++j) {
                const int gk = k0 + (tx << 2) + j;
                Ah[(long)gk * 512 + gi] = vals[i][j];
            }
        }
    }
}

// ---------------------------------------------------------------------------
// Row degree: R[row] = 1/sqrt(clip(1 + sum_k A[row,k], 1e-6)) ; one wave/row
// ---------------------------------------------------------------------------
__global__ __launch_bounds__(256)
void rowsum_kernel(const float* __restrict__ A, float* __restrict__ R)
{
    const int row = (blockIdx.x << 2) + (threadIdx.x >> 6);
    const int lane = threadIdx.x & 63;
    const float* p = A + (long)row * 512;
    float s = 0.0f;
    #pragma unroll
    for (int t = 0; t < 8; ++t) s += p[lane + (t << 6)];
    #pragma unroll
    for (int off = 32; off; off >>= 1) s += __shfl_xor(s, off, 64);
    if (lane == 0) R[row] = 1.0f / sqrtf(fmaxf(1.0f + s, 1e-6f));
}

// ---------------------------------------------------------------------------
// A_hat[i,k] = R[i]*R[k]*(A[i,k] + (i==k)) in place
// ---------------------------------------------------------------------------
__global__ __launch_bounds__(256)
void ahat_kernel(float* __restrict__ A, const float* __restrict__ R)
{
    const long i4 = ((long)blockIdx.x * 256 + threadIdx.x) << 2;
    const long off = i4 & 262143;
    const long bh = i4 >> 18;
    const int i = (int)(off >> 9);
    const int k = (int)(off & 511);
    const float ri = R[(bh << 9) + i];
    const float* Rk = R + (bh << 9) + k;
    float4 v = *(float4*)(A + i4);
    v.x = ri * Rk[0] * (v.x + ((k + 0) == i ? 1.0f : 0.0f));
    v.y = ri * Rk[1] * (v.y + ((k + 1) == i ? 1.0f : 0.0f));
    v.z = ri * Rk[2] * (v.z + ((k + 2) == i ? 1.0f : 0.0f));
    v.w = ri * Rk[3] * (v.w + ((k + 3) == i ? 1.0f : 0.0f));
    *(float4*)(A + i4) = v;
}

// ---------------------------------------------------------------------------
// Row softmax over 512, in place. One block (256 threads) per row.
// ---------------------------------------------------------------------------
__global__ __launch_bounds__(256)
void softmax_kernel(float* __restrict__ P)
{
    float* p = P + (long)blockIdx.x * 512;
    const int t = threadIdx.x;
    float v0 = p[t], v1 = p[t + 256];
    __shared__ float red[256];
    red[t] = fmaxf(v0, v1);
    __syncthreads();
    #pragma unroll
    for (int s = 128; s > 0; s >>= 1) {
        if (t < s) red[t] = fmaxf(red[t], red[t + s]);
        __syncthreads();
    }
    const float mx = red[0];
    __syncthreads();
    const float e0 = __expf(v0 - mx), e1 = __expf(v1 - mx);
    red[t] = e0 + e1;
    __syncthreads();
    #pragma unroll
    for (int s = 128; s > 0; s >>= 1) {
        if (t < s) red[t] += red[t + s];
        __syncthreads();
    }
    const float inv = 1.0f / red[0];
    p[t] = e0 * inv;
    p[t + 256] = e1 * inv;
}

// ---------------------------------------------------------------------------
// O = P @ V per head: M=512, N=64, K=512. 64x64 tile, 4x4 micro.
// ---------------------------------------------------------------------------
__global__ __launch_bounds__(256)
void gemm_pv(const float* __restrict__ P, const float* __restrict__ V,
             float* __restrict__ O)
{
    const int bh = blockIdx.z;
    const float* Pp = P + (long)bh * 262144;
    const float* Vp = V + (long)bh * 32768;
    float* Op = O + (long)bh * 32768;

    __shared__ float Ps[16][68];
    __shared__ float Vs[16][68];

    const int tid = threadIdx.x;
    const int tx = tid & 15, ty = tid >> 4;
    const int m0 = blockIdx.y << 6;

    float acc[4][4] = {};

    for (int k0 = 0; k0 < 512; k0 += 16) {
        const int r = tid >> 2, c4 = (tid & 3) << 2;
        float4 av = *(const float4*)(Pp + (long)(m0 + r) * 512 + k0 + c4);
        const int rb = tid >> 4, cb = (tid & 15) << 2;
        float4 bv = *(const float4*)(Vp + (long)(k0 + rb) * 64 + cb);

        Ps[c4 + 0][r] = av.x; Ps[c4 + 1][r] = av.y;
        Ps[c4 + 2][r] = av.z; Ps[c4 + 3][r] = av.w;
        *(float4*)&Vs[rb][cb] = bv;
        __syncthreads();

        #pragma unroll
        for (int kk = 0; kk < 16; ++kk) {
            float a[4], b[4];
            *(float4*)a = *(const float4*)&Ps[kk][ty << 2];
            *(float4*)b = *(const float4*)&Vs[kk][tx << 2];
            #pragma unroll
            for (int i = 0; i < 4; ++i)
                #pragma unroll
                for (int j = 0; j < 4; ++j)
                    acc[i][j] = fmaf(a[i], b[j], acc[i][j]);
        }
        __syncthreads();
    }

    #pragma unroll
    for (int i = 0; i < 4; ++i) {
        float4 v = make_float4(acc[i][0], acc[i][1], acc[i][2], acc[i][3]);
        *(float4*)(Op + (long)(m0 + (ty << 2) + i) * 64 + (tx << 2)) = v;
    }
}

// ---------------------------------------------------------------------------
// Transpose O [BH][L][HD] -> Of [B][L][H*HD]
// ---------------------------------------------------------------------------
__global__ __launch_bounds__(256)
void transO_kernel(const float* __restrict__ O, float* __restrict__ Of)
{
    const long i4 = ((long)blockIdx.x * 256 + threadIdx.x) << 2;
    const int d = (int)(i4 & 63);
    const long rest = i4 >> 6;          // (b*8+h)*512 + l
    const int l = (int)(rest & 511);
    const long bh = rest >> 9;
    const int h = (int)(bh & 7);
    const long b = bh >> 3;
    const float4 v = *(const float4*)(O + i4);
    *(float4*)(Of + (((b << 9) + l) << 9) + (h << 6) + d) = v;
}

// ---------------------------------------------------------------------------
extern "C" void kernel_launch(void* const* d_in, const int* in_sizes, int n_in,
                              void* d_out, int out_size, void* d_ws, size_t ws_size,
                              hipStream_t stream)
{
    const float* x  = (const float*)d_in[0];
    const float* Wq = (const float*)d_in[1];
    const float* Wk = (const float*)d_in[2];
    const float* Wv = (const float*)d_in[3];
    const float* Wo = (const float*)d_in[4];
    float* out = (float*)d_out;

    float* ws = (float*)d_ws;
    float* Q  = ws;                       // 1M floats
    float* Kt = Q  + (1u << 20);          // 1M
    float* V  = Kt + (1u << 20);          // 1M
    float* S  = V  + (1u << 20);          // 8M
    float* Am = S  + (8u << 20);          // 8M
    float* T  = Am + (8u << 20);          // 8M
    float* R  = T  + (8u << 20);          // 16K
    float* O  = R  + 16384;               // 1M

    dim3 blk(256);

    // 1) Q/K/V projections: [B*L,512] x [512,512] -> [BH][L][HD]
    gemm128<0, 1><<<dim3(4, 16, 1), blk, 0, stream>>>(x, Wq, Q,  2048, 512, 512, 0, 0, 0, 1.0f);
    gemm128<0, 1><<<dim3(4, 16, 1), blk, 0, stream>>>(x, Wk, Kt, 2048, 512, 512, 0, 0, 0, 1.0f);
    gemm128<0, 1><<<dim3(4, 16, 1), blk, 0, stream>>>(x, Wv, V,  2048, 512, 512, 0, 0, 0, 1.0f);

    // 2) S = Q K^T per head
    gemm128<1, 0><<<dim3(4, 4, 32), blk, 0, stream>>>(Q, Kt, S, 512, 512, 64,
                                                      32768, 32768, 262144, 1.0f);

    // 3) adjacency A (diag 0, thresholded, /L), symmetric upper-triangle tiles
    adj_kernel<<<dim3(36, 1, 32), blk, 0, stream>>>(S, Am);

    // 4) row degrees -> R = D^-1/2
    rowsum_kernel<<<dim3(4096), blk, 0, stream>>>(Am, R);

    // 5) A_hat in place
    ahat_kernel<<<dim3(8192), blk, 0, stream>>>(Am, R);

    // 6) T = A_hat @ S
    gemm128<0, 0><<<dim3(4, 4, 32), blk, 0, stream>>>(Am, S, T, 512, 512, 512,
                                                      262144, 262144, 262144, 1.0f);

    // 7) J = T @ A_hat^T / 8  (into S buffer; A_hat is symmetric but use BT=1
    //    to keep the exact same operand values as the reference contraction)
    gemm128<1, 0><<<dim3(4, 4, 32), blk, 0, stream>>>(T, Am, S, 512, 512, 512,
                                                      262144, 262144, 262144, 0.125f);

    // 8) softmax rows of J (in place in S)
    softmax_kernel<<<dim3(16384), blk, 0, stream>>>(S);

    // 9) O = P @ V
    gemm_pv<<<dim3(1, 8, 32), blk, 0, stream>>>(S, V, O);

    // 10) O -> Of (reuse Q buffer)
    transO_kernel<<<dim3(1024), blk, 0, stream>>>(O, Q);

    // 11) out = Of @ Wo
    gemm128<0, 0><<<dim3(4, 16, 1), blk, 0, stream>>>(Q, Wo, out, 2048, 512, 512,
                                                      0, 0, 0, 1.0f);
}

// Round 3
// 578.119 us; speedup vs baseline: 1.7618x; 1.6441x over previous
//
#include <hip/hip_runtime.h>
#include <math.h>

// Problem constants: B=4, H=8, L=512, HD=64, D=512, RHO=0.1
// Workspace (floats):
//   Q   : 1M   [BH][512][64]
//   Kt  : 1M
//   V   : 1M
//   S   : 8M   [BH][512][512]  (scores -> later J -> softmax'd P)
//   Am  : 8M   (adj partial 0 -> A_hat)
//   T   : 8M   (adj partial 1 -> A_hat@S)
//   R   : 16K  (row inv-sqrt degrees)
//   O   : 1M

typedef __attribute__((ext_vector_type(8))) short short8v;
typedef __attribute__((ext_vector_type(4))) float f32x4;

// ---------------------------------------------------------------------------
// Generic 128x128-tile fp32 GEMM, BK=16, 256 threads, 8x8 micro-tile.
// BT=1: C = A * B^T (B is N x K row-major). BT=0: C = A * B (K x N).
// ---------------------------------------------------------------------------
template<int BT>
__global__ __launch_bounds__(256)
void gemm128(const float* __restrict__ Ap, const float* __restrict__ Bp,
             float* __restrict__ Cp, int M, int N, int K,
             long sA, long sB, long sC, float scale)
{
    const float* A  = Ap + (long)blockIdx.z * sA;
    const float* Bm = Bp + (long)blockIdx.z * sB;
    float*       C  = Cp + (long)blockIdx.z * sC;

    __shared__ float As[16][132];
    __shared__ float Bs[16][132];

    const int tid = threadIdx.x;
    const int tx = tid & 15, ty = tid >> 4;
    const int m0 = blockIdx.y << 7, n0 = blockIdx.x << 7;

    float acc[8][8] = {};

    for (int k0 = 0; k0 < K; k0 += 16) {
        const int r = tid >> 1, c = (tid & 1) << 3;
        float4 a0 = *(const float4*)(A + (long)(m0 + r) * K + k0 + c);
        float4 a1 = *(const float4*)(A + (long)(m0 + r) * K + k0 + c + 4);
        float4 b0, b1;
        int rb = 0, cb = 0;
        if (BT) {
            b0 = *(const float4*)(Bm + (long)(n0 + r) * K + k0 + c);
            b1 = *(const float4*)(Bm + (long)(n0 + r) * K + k0 + c + 4);
        } else {
            rb = tid >> 4; cb = (tid & 15) << 3;
            b0 = *(const float4*)(Bm + (long)(k0 + rb) * N + n0 + cb);
            b1 = *(const float4*)(Bm + (long)(k0 + rb) * N + n0 + cb + 4);
        }

        As[c + 0][r] = a0.x; As[c + 1][r] = a0.y; As[c + 2][r] = a0.z; As[c + 3][r] = a0.w;
        As[c + 4][r] = a1.x; As[c + 5][r] = a1.y; As[c + 6][r] = a1.z; As[c + 7][r] = a1.w;
        if (BT) {
            Bs[c + 0][r] = b0.x; Bs[c + 1][r] = b0.y; Bs[c + 2][r] = b0.z; Bs[c + 3][r] = b0.w;
            Bs[c + 4][r] = b1.x; Bs[c + 5][r] = b1.y; Bs[c + 6][r] = b1.z; Bs[c + 7][r] = b1.w;
        } else {
            *(float4*)&Bs[rb][cb]     = b0;
            *(float4*)&Bs[rb][cb + 4] = b1;
        }
        __syncthreads();

        #pragma unroll
        for (int kk = 0; kk < 16; ++kk) {
            float a[8], b[8];
            *(float4*)&a[0] = *(const float4*)&As[kk][ty << 3];
            *(float4*)&a[4] = *(const float4*)&As[kk][(ty << 3) + 4];
            *(float4*)&b[0] = *(const float4*)&Bs[kk][tx << 3];
            *(float4*)&b[4] = *(const float4*)&Bs[kk][(tx << 3) + 4];
            #pragma unroll
            for (int i = 0; i < 8; ++i)
                #pragma unroll
                for (int j = 0; j < 8; ++j)
                    acc[i][j] = fmaf(a[i], b[j], acc[i][j]);
        }
        __syncthreads();
    }

    #pragma unroll
    for (int i = 0; i < 8; ++i) {
        const int m = m0 + (ty << 3) + i;
        #pragma unroll
        for (int j4 = 0; j4 < 8; j4 += 4) {
            float4 v = make_float4(acc[i][j4 + 0] * scale, acc[i][j4 + 1] * scale,
                                   acc[i][j4 + 2] * scale, acc[i][j4 + 3] * scale);
            *(float4*)(C + (long)m * N + n0 + (tx << 3) + j4) = v;
        }
    }
}

// ---------------------------------------------------------------------------
// Fused QKV projection: x[2048x512] x {Wq|Wk|Wv}[512x512] -> QKV buffers
// laid out [BH][512][64], Q at +0, K at +1M, V at +2M. One launch, 192 blocks.
// ---------------------------------------------------------------------------
__global__ __launch_bounds__(256)
void gemm_qkv(const float* __restrict__ x, const float* __restrict__ Wq,
              const float* __restrict__ Wk, const float* __restrict__ Wv,
              float* __restrict__ QKV)
{
    const int m0 = blockIdx.y << 7;          // 16 m-tiles (M=2048)
    const int ng = blockIdx.x << 7;          // 12 n-tiles (Nglob=1536)
    const float* W = (ng < 512) ? Wq : (ng < 1024) ? Wk : Wv;
    const int n0 = ng & 511;
    float* C = QKV + (long)(ng >> 9) * (1 << 20);

    __shared__ float As[16][132];
    __shared__ float Bs[16][132];

    const int tid = threadIdx.x;
    const int tx = tid & 15, ty = tid >> 4;

    float acc[8][8] = {};

    for (int k0 = 0; k0 < 512; k0 += 16) {
        const int r = tid >> 1, c = (tid & 1) << 3;
        float4 a0 = *(const float4*)(x + (long)(m0 + r) * 512 + k0 + c);
        float4 a1 = *(const float4*)(x + (long)(m0 + r) * 512 + k0 + c + 4);
        const int rb = tid >> 4, cb = (tid & 15) << 3;
        float4 b0 = *(const float4*)(W + (long)(k0 + rb) * 512 + n0 + cb);
        float4 b1 = *(const float4*)(W + (long)(k0 + rb) * 512 + n0 + cb + 4);

        As[c + 0][r] = a0.x; As[c + 1][r] = a0.y; As[c + 2][r] = a0.z; As[c + 3][r] = a0.w;
        As[c + 4][r] = a1.x; As[c + 5][r] = a1.y; As[c + 6][r] = a1.z; As[c + 7][r] = a1.w;
        *(float4*)&Bs[rb][cb]     = b0;
        *(float4*)&Bs[rb][cb + 4] = b1;
        __syncthreads();

        #pragma unroll
        for (int kk = 0; kk < 16; ++kk) {
            float a[8], b[8];
            *(float4*)&a[0] = *(const float4*)&As[kk][ty << 3];
            *(float4*)&a[4] = *(const float4*)&As[kk][(ty << 3) + 4];
            *(float4*)&b[0] = *(const float4*)&Bs[kk][tx << 3];
            *(float4*)&b[4] = *(const float4*)&Bs[kk][(tx << 3) + 4];
            #pragma unroll
            for (int i = 0; i < 8; ++i)
                #pragma unroll
                for (int j = 0; j < 8; ++j)
                    acc[i][j] = fmaf(a[i], b[j], acc[i][j]);
        }
        __syncthreads();
    }

    #pragma unroll
    for (int i = 0; i < 8; ++i) {
        const int m = m0 + (ty << 3) + i;
        const int b = m >> 9, l = m & 511;
        #pragma unroll
        for (int j4 = 0; j4 < 8; j4 += 4) {
            const int nl = n0 + (tx << 3) + j4;
            const int h = nl >> 6, d = nl & 63;
            float4 v = make_float4(acc[i][j4 + 0], acc[i][j4 + 1],
                                   acc[i][j4 + 2], acc[i][j4 + 3]);
            *(float4*)(C + ((long)((b * 8 + h) * 512 + l)) * 64 + d) = v;
        }
    }
}

// ---------------------------------------------------------------------------
// Adjacency partials: P[i,k] = sum_{j in half} u, u=(S_ij/8)(S_kj/8) if u>0.1,
// diag 0, UNSCALED (the 1/512 is applied at combine time). Symmetric ->
// upper-triangle 64x64 tile pairs (36), mirrored write. blockIdx.y = j-half.
// ---------------------------------------------------------------------------
__global__ __launch_bounds__(256)
void adj_kernel(const float* __restrict__ S, float* __restrict__ P0,
                float* __restrict__ P1)
{
    const int bh = blockIdx.z;
    const float* __restrict__ Sh = S + (long)bh * 262144;
    float* __restrict__ Ph = ((blockIdx.y == 0) ? P0 : P1) + (long)bh * 262144;
    const int jbase = blockIdx.y << 8;

    int ti = 0, rem = blockIdx.x;
    while (rem >= 8 - ti) { rem -= 8 - ti; ++ti; }
    const int tk = ti + rem;

    __shared__ float Ls[16][68];
    __shared__ float Rs[16][68];

    const int tid = threadIdx.x;
    const int tx = tid & 15, ty = tid >> 4;
    const int i0 = ti << 6, k0 = tk << 6;

    float acc[4][4] = {};

    for (int j0 = jbase; j0 < jbase + 256; j0 += 16) {
        const int r = tid >> 2, c4 = (tid & 3) << 2;
        float4 av = *(const float4*)(Sh + (long)(i0 + r) * 512 + j0 + c4);
        float4 bv = *(const float4*)(Sh + (long)(k0 + r) * 512 + j0 + c4);

        Ls[c4 + 0][r] = av.x * 0.125f; Ls[c4 + 1][r] = av.y * 0.125f;
        Ls[c4 + 2][r] = av.z * 0.125f; Ls[c4 + 3][r] = av.w * 0.125f;
        Rs[c4 + 0][r] = bv.x * 0.125f; Rs[c4 + 1][r] = bv.y * 0.125f;
        Rs[c4 + 2][r] = bv.z * 0.125f; Rs[c4 + 3][r] = bv.w * 0.125f;
        __syncthreads();

        #pragma unroll
        for (int jj = 0; jj < 16; ++jj) {
            float a[4], b[4];
            *(float4*)a = *(const float4*)&Ls[jj][ty << 2];
            *(float4*)b = *(const float4*)&Rs[jj][tx << 2];
            #pragma unroll
            for (int i = 0; i < 4; ++i)
                #pragma unroll
                for (int j = 0; j < 4; ++j) {
                    const float u = a[i] * b[j];
                    const float t = 0.1f - u;
                    const int  m = __float_as_int(t) >> 31;
                    acc[i][j] += __int_as_float(__float_as_int(u) & m);
                }
        }
        __syncthreads();
    }

    #pragma unroll
    for (int i = 0; i < 4; ++i) {
        const int gi = i0 + (ty << 2) + i;
        float4 v;
        float* pv = &v.x;
        #pragma unroll
        for (int j = 0; j < 4; ++j) {
            const int gk = k0 + (tx << 2) + j;
            pv[j] = (gi == gk) ? 0.0f : acc[i][j];
        }
        *(float4*)(Ph + (long)gi * 512 + k0 + (tx << 2)) = v;
    }

    if (ti != tk) {
        #pragma unroll
        for (int i = 0; i < 4; ++i) {
            const int gi = i0 + (ty << 2) + i;
            #pragma unroll
            for (int j = 0; j < 4; ++j) {
                const int gk = k0 + (tx << 2) + j;
                Ph[(long)gk * 512 + gi] = acc[i][j];
            }
        }
    }
}

// ---------------------------------------------------------------------------
// Row degree from partials: R[row] = 1/sqrt(clip(1 + (sum(P0+P1))/512, 1e-6))
// ---------------------------------------------------------------------------
__global__ __launch_bounds__(256)
void rowsum_kernel(const float* __restrict__ P0, const float* __restrict__ P1,
                   float* __restrict__ R)
{
    const int row = (blockIdx.x << 2) + (threadIdx.x >> 6);
    const int lane = threadIdx.x & 63;
    const float* p0 = P0 + (long)row * 512;
    const float* p1 = P1 + (long)row * 512;
    float s = 0.0f;
    #pragma unroll
    for (int t = 0; t < 8; ++t) s += p0[lane + (t << 6)] + p1[lane + (t << 6)];
    #pragma unroll
    for (int off = 32; off; off >>= 1) s += __shfl_xor(s, off, 64);
    if (lane == 0) R[row] = 1.0f / sqrtf(fmaxf(1.0f + s * (1.0f / 512.0f), 1e-6f));
}

// ---------------------------------------------------------------------------
// A_hat[i,k] = R[i]*R[k]*((P0+P1)/512 + (i==k)) -> written to P0
// ---------------------------------------------------------------------------
__global__ __launch_bounds__(256)
void ahat_kernel(float* __restrict__ P0, const float* __restrict__ P1,
                 const float* __restrict__ R)
{
    const long i4 = ((long)blockIdx.x * 256 + threadIdx.x) << 2;
    const long off = i4 & 262143;
    const long bh = i4 >> 18;
    const int i = (int)(off >> 9);
    const int k = (int)(off & 511);
    const float ri = R[(bh << 9) + i];
    const float* Rk = R + (bh << 9) + k;
    const float inv = 1.0f / 512.0f;
    float4 v0 = *(float4*)(P0 + i4);
    float4 v1 = *(const float4*)(P1 + i4);
    v0.x = ri * Rk[0] * ((v0.x + v1.x) * inv + ((k + 0) == i ? 1.0f : 0.0f));
    v0.y = ri * Rk[1] * ((v0.y + v1.y) * inv + ((k + 1) == i ? 1.0f : 0.0f));
    v0.z = ri * Rk[2] * ((v0.z + v1.z) * inv + ((k + 2) == i ? 1.0f : 0.0f));
    v0.w = ri * Rk[3] * ((v0.w + v1.w) * inv + ((k + 3) == i ? 1.0f : 0.0f));
    *(float4*)(P0 + i4) = v0;
}

// ---------------------------------------------------------------------------
// Split-bf16 MFMA GEMM, per-head batched 512x512x512.
// BT=0: C = A @ B   (B staged transposed: Bs[n][k] = B[k][n])
// BT=1: C = A @ B^T (Bs[n][k] = B[n][k], direct row staging)
// fp32 operands split on the fly: x = hi(bf16 trunc) + lo(bf16 trunc of rem);
// acc += Ahi*Bhi + Ahi*Blo + Alo*Bhi  (lo*lo dropped, rel err ~2e-5).
// 128x128 tile, 4 waves (2x2), each wave 64x64 = 4x4 frags 16x16, K-step 32.
// LDS slots XOR-swizzled: slot = g ^ (row&3) ^ ((row>>2)&3).
// ---------------------------------------------------------------------------
template<int BT>
__global__ __launch_bounds__(256)
void gemm_mfma(const float* __restrict__ Ap, const float* __restrict__ Bp,
               float* __restrict__ Cp, float scale)
{
    const int bh = blockIdx.z;
    const float* __restrict__ A = Ap + (long)bh * 262144;
    const float* __restrict__ B = Bp + (long)bh * 262144;
    float* __restrict__ C = Cp + (long)bh * 262144;
    const int m0 = blockIdx.y << 7, n0 = blockIdx.x << 7;

    __shared__ short Ah[128 * 32], Al[128 * 32], Bh[128 * 32], Bl[128 * 32];

    const int tid = threadIdx.x;
    const int lane = tid & 63, wv = tid >> 6;
    const int wr = wv >> 1, wc = wv & 1;

    f32x4 acc[4][4] = {};

    for (int k0 = 0; k0 < 512; k0 += 32) {
        // ---- stage A: rows m0..m0+127, k0..k0+31 ----
        {
            const int row = tid >> 1;
            const int swz = (row & 3) ^ ((row >> 2) & 3);
            #pragma unroll
            for (int gg = 0; gg < 2; ++gg) {
                const int g = ((tid & 1) << 1) + gg;
                const float* src = A + (long)(m0 + row) * 512 + k0 + (g << 3);
                float v[8];
                *(float4*)&v[0] = *(const float4*)src;
                *(float4*)&v[4] = *(const float4*)(src + 4);
                unsigned hi[4], lo[4];
                #pragma unroll
                for (int q = 0; q < 4; ++q) {
                    const unsigned b0 = __float_as_uint(v[2 * q])     & 0xFFFF0000u;
                    const unsigned b1 = __float_as_uint(v[2 * q + 1]) & 0xFFFF0000u;
                    const float d0 = v[2 * q]     - __uint_as_float(b0);
                    const float d1 = v[2 * q + 1] - __uint_as_float(b1);
                    hi[q] = (b0 >> 16) | b1;
                    lo[q] = (__float_as_uint(d0) >> 16) | (__float_as_uint(d1) & 0xFFFF0000u);
                }
                const int off = row * 32 + ((g ^ swz) << 3);
                *(uint4*)&Ah[off] = *(uint4*)hi;
                *(uint4*)&Al[off] = *(uint4*)lo;
            }
        }
        // ---- stage B into Bs[n][k] ----
        if (BT) {
            const int row = tid >> 1;   // n index
            const int swz = (row & 3) ^ ((row >> 2) & 3);
            #pragma unroll
            for (int gg = 0; gg < 2; ++gg) {
                const int g = ((tid & 1) << 1) + gg;
                const float* src = B + (long)(n0 + row) * 512 + k0 + (g << 3);
                float v[8];
                *(float4*)&v[0] = *(const float4*)src;
                *(float4*)&v[4] = *(const float4*)(src + 4);
                unsigned hi[4], lo[4];
                #pragma unroll
                for (int q = 0; q < 4; ++q) {
                    const unsigned b0 = __float_as_uint(v[2 * q])     & 0xFFFF0000u;
                    const unsigned b1 = __float_as_uint(v[2 * q + 1]) & 0xFFFF0000u;
                    const float d0 = v[2 * q]     - __uint_as_float(b0);
                    const float d1 = v[2 * q + 1] - __uint_as_float(b1);
                    hi[q] = (b0 >> 16) | b1;
                    lo[q] = (__float_as_uint(d0) >> 16) | (__float_as_uint(d1) & 0xFFFF0000u);
                }
                const int off = row * 32 + ((g ^ swz) << 3);
                *(uint4*)&Bh[off] = *(uint4*)hi;
                *(uint4*)&Bl[off] = *(uint4*)lo;
            }
        } else {
            const int n = tid & 127;
            const int swz = (n & 3) ^ ((n >> 2) & 3);
            #pragma unroll
            for (int gg = 0; gg < 2; ++gg) {
                const int g = ((tid >> 7) << 1) + gg;
                float v[8];
                #pragma unroll
                for (int e = 0; e < 8; ++e)
                    v[e] = B[(long)(k0 + (g << 3) + e) * 512 + n0 + n];
                unsigned hi[4], lo[4];
                #pragma unroll
                for (int q = 0; q < 4; ++q) {
                    const unsigned b0 = __float_as_uint(v[2 * q])     & 0xFFFF0000u;
                    const unsigned b1 = __float_as_uint(v[2 * q + 1]) & 0xFFFF0000u;
                    const float d0 = v[2 * q]     - __uint_as_float(b0);
                    const float d1 = v[2 * q + 1] - __uint_as_float(b1);
                    hi[q] = (b0 >> 16) | b1;
                    lo[q] = (__float_as_uint(d0) >> 16) | (__float_as_uint(d1) & 0xFFFF0000u);
                }
                const int off = n * 32 + ((g ^ swz) << 3);
                *(uint4*)&Bh[off] = *(uint4*)hi;
                *(uint4*)&Bl[off] = *(uint4*)lo;
            }
        }
        __syncthreads();

        // ---- compute: A frag row = lane&15, k = 8*(lane>>4)+e ----
        {
            const int r = lane & 15, g = lane >> 4;
            const int lswz = (r & 3) ^ ((r >> 2) & 3);
            const int gslot = ((g ^ lswz) << 3);
            const int abase = ((wr << 6) + r) * 32 + gslot;
            const int bbase = ((wc << 6) + r) * 32 + gslot;
            short8v afh[4], afl[4], bfh[4], bfl[4];
            #pragma unroll
            for (int f = 0; f < 4; ++f) {
                afh[f] = *(short8v*)&Ah[abase + f * 512];
                afl[f] = *(short8v*)&Al[abase + f * 512];
                bfh[f] = *(short8v*)&Bh[bbase + f * 512];
                bfl[f] = *(short8v*)&Bl[bbase + f * 512];
            }
            #pragma unroll
            for (int fi = 0; fi < 4; ++fi)
                #pragma unroll
                for (int fj = 0; fj < 4; ++fj) {
                    acc[fi][fj] = __builtin_amdgcn_mfma_f32_16x16x32_bf16(
                        afh[fi], bfh[fj], acc[fi][fj], 0, 0, 0);
                    acc[fi][fj] = __builtin_amdgcn_mfma_f32_16x16x32_bf16(
                        afh[fi], bfl[fj], acc[fi][fj], 0, 0, 0);
                    acc[fi][fj] = __builtin_amdgcn_mfma_f32_16x16x32_bf16(
                        afl[fi], bfh[fj], acc[fi][fj], 0, 0, 0);
                }
        }
        __syncthreads();
    }

    // epilogue: C/D layout col = lane&15, row = (lane>>4)*4 + reg  [m89/m91]
    const int r = lane & 15, g = lane >> 4;
    #pragma unroll
    for (int fi = 0; fi < 4; ++fi) {
        const int gr0 = m0 + (wr << 6) + fi * 16 + g * 4;
        #pragma unroll
        for (int fj = 0; fj < 4; ++fj) {
            const int gc = n0 + (wc << 6) + fj * 16 + r;
            #pragma unroll
            for (int q = 0; q < 4; ++q)
                C[(long)(gr0 + q) * 512 + gc] = acc[fi][fj][q] * scale;
        }
    }
}

// ---------------------------------------------------------------------------
// Row softmax over 512, in place.
// ---------------------------------------------------------------------------
__global__ __launch_bounds__(256)
void softmax_kernel(float* __restrict__ P)
{
    float* p = P + (long)blockIdx.x * 512;
    const int t = threadIdx.x;
    float v0 = p[t], v1 = p[t + 256];
    __shared__ float red[256];
    red[t] = fmaxf(v0, v1);
    __syncthreads();
    #pragma unroll
    for (int s = 128; s > 0; s >>= 1) {
        if (t < s) red[t] = fmaxf(red[t], red[t + s]);
        __syncthreads();
    }
    const float mx = red[0];
    __syncthreads();
    const float e0 = __expf(v0 - mx), e1 = __expf(v1 - mx);
    red[t] = e0 + e1;
    __syncthreads();
    #pragma unroll
    for (int s = 128; s > 0; s >>= 1) {
        if (t < s) red[t] += red[t + s];
        __syncthreads();
    }
    const float inv = 1.0f / red[0];
    p[t] = e0 * inv;
    p[t + 256] = e1 * inv;
}

// ---------------------------------------------------------------------------
// O = P @ V per head: M=512, N=64, K=512. 64x64 tile, 4x4 micro.
// ---------------------------------------------------------------------------
__global__ __launch_bounds__(256)
void gemm_pv(const float* __restrict__ P, const float* __restrict__ V,
             float* __restrict__ O)
{
    const int bh = blockIdx.z;
    const float* Pp = P + (long)bh * 262144;
    const float* Vp = V + (long)bh * 32768;
    float* Op = O + (long)bh * 32768;

    __shared__ float Ps[16][68];
    __shared__ float Vs[16][68];

    const int tid = threadIdx.x;
    const int tx = tid & 15, ty = tid >> 4;
    const int m0 = blockIdx.y << 6;

    float acc[4][4] = {};

    for (int k0 = 0; k0 < 512; k0 += 16) {
        const int r = tid >> 2, c4 = (tid & 3) << 2;
        float4 av = *(const float4*)(Pp + (long)(m0 + r) * 512 + k0 + c4);
        const int rb = tid >> 4, cb = (tid & 15) << 2;
        float4 bv = *(const float4*)(Vp + (long)(k0 + rb) * 64 + cb);

        Ps[c4 + 0][r] = av.x; Ps[c4 + 1][r] = av.y;
        Ps[c4 + 2][r] = av.z; Ps[c4 + 3][r] = av.w;
        *(float4*)&Vs[rb][cb] = bv;
        __syncthreads();

        #pragma unroll
        for (int kk = 0; kk < 16; ++kk) {
            float a[4], b[4];
            *(float4*)a = *(const float4*)&Ps[kk][ty << 2];
            *(float4*)b = *(const float4*)&Vs[kk][tx << 2];
            #pragma unroll
            for (int i = 0; i < 4; ++i)
                #pragma unroll
                for (int j = 0; j < 4; ++j)
                    acc[i][j] = fmaf(a[i], b[j], acc[i][j]);
        }
        __syncthreads();
    }

    #pragma unroll
    for (int i = 0; i < 4; ++i) {
        float4 v = make_float4(acc[i][0], acc[i][1], acc[i][2], acc[i][3]);
        *(float4*)(Op + (long)(m0 + (ty << 2) + i) * 64 + (tx << 2)) = v;
    }
}

// ---------------------------------------------------------------------------
// Transpose O [BH][L][HD] -> Of [B][L][H*HD]
// ---------------------------------------------------------------------------
__global__ __launch_bounds__(256)
void transO_kernel(const float* __restrict__ O, float* __restrict__ Of)
{
    const long i4 = ((long)blockIdx.x * 256 + threadIdx.x) << 2;
    const int d = (int)(i4 & 63);
    const long rest = i4 >> 6;
    const int l = (int)(rest & 511);
    const long bh = rest >> 9;
    const int h = (int)(bh & 7);
    const long b = bh >> 3;
    const float4 v = *(const float4*)(O + i4);
    *(float4*)(Of + (((b << 9) + l) << 9) + (h << 6) + d) = v;
}

// ---------------------------------------------------------------------------
extern "C" void kernel_launch(void* const* d_in, const int* in_sizes, int n_in,
                              void* d_out, int out_size, void* d_ws, size_t ws_size,
                              hipStream_t stream)
{
    const float* x  = (const float*)d_in[0];
    const float* Wq = (const float*)d_in[1];
    const float* Wk = (const float*)d_in[2];
    const float* Wv = (const float*)d_in[3];
    const float* Wo = (const float*)d_in[4];
    float* out = (float*)d_out;

    float* ws = (float*)d_ws;
    float* Q  = ws;                       // 1M floats (QKV base)
    float* Kt = Q  + (1u << 20);          // 1M
    float* V  = Kt + (1u << 20);          // 1M
    float* S  = V  + (1u << 20);          // 8M
    float* Am = S  + (8u << 20);          // 8M (adj partial 0 -> A_hat)
    float* T  = Am + (8u << 20);          // 8M (adj partial 1 -> A_hat@S)
    float* R  = T  + (8u << 20);          // 16K
    float* O  = R  + 16384;               // 1M

    dim3 blk(256);

    // 1) fused QKV projections
    gemm_qkv<<<dim3(12, 16, 1), blk, 0, stream>>>(x, Wq, Wk, Wv, Q);

    // 2) S = Q K^T per head
    gemm128<1><<<dim3(4, 4, 32), blk, 0, stream>>>(Q, Kt, S, 512, 512, 64,
                                                   32768, 32768, 262144, 1.0f);

    // 3) adjacency partials (j-split x2)
    adj_kernel<<<dim3(36, 2, 32), blk, 0, stream>>>(S, Am, T);

    // 4) row degrees -> R
    rowsum_kernel<<<dim3(4096), blk, 0, stream>>>(Am, T, R);

    // 5) A_hat (combined partials) -> Am
    ahat_kernel<<<dim3(8192), blk, 0, stream>>>(Am, T, R);

    // 6) T = A_hat @ S   (split-bf16 MFMA)
    gemm_mfma<0><<<dim3(4, 4, 32), blk, 0, stream>>>(Am, S, T, 1.0f);

    // 7) J = T @ A_hat^T / 8 -> S
    gemm_mfma<1><<<dim3(4, 4, 32), blk, 0, stream>>>(T, Am, S, 0.125f);

    // 8) softmax rows of J
    softmax_kernel<<<dim3(16384), blk, 0, stream>>>(S);

    // 9) O = P @ V
    gemm_pv<<<dim3(1, 8, 32), blk, 0, stream>>>(S, V, O);

    // 10) O -> Of (reuse Q)
    transO_kernel<<<dim3(1024), blk, 0, stream>>>(O, Q);

    // 11) out = Of @ Wo
    gemm128<0><<<dim3(4, 16, 1), blk, 0, stream>>>(Q, Wo, out, 2048, 512, 512,
                                                   0, 0, 0, 1.0f);
}